// Round 9
// baseline (1030.512 us; speedup 1.0000x reference)
//
#include <hip/hip_runtime.h>

#define TT 2048
#define SS 128
#define DMAXX 128
#define NBATCH 64

typedef float f2 __attribute__((ext_vector_type(2)));

__device__ __forceinline__ float fexp2(float x){ return __builtin_amdgcn_exp2f(x); }
__device__ __forceinline__ float flog2(float x){ return __builtin_amdgcn_logf(x); }
__device__ __forceinline__ float frcp (float x){ return __builtin_amdgcn_rcpf(x); }
__device__ __forceinline__ f2 pkfma(f2 a, f2 b, f2 c){ return __builtin_elementwise_fma(a, b, c); }

template<int CTRL>
__device__ __forceinline__ float dppf(float x) {
    int i = __float_as_int(x);
    return __int_as_float(__builtin_amdgcn_update_dpp(i, i, CTRL, 0xF, 0xF, false));
}
template<int CTRL>
__device__ __forceinline__ float dppzf(float x) {   // bound_ctrl: OOB source lanes read 0
    int i = __float_as_int(x);
    return __int_as_float(__builtin_amdgcn_update_dpp(0, i, CTRL, 0xF, 0xF, true));
}
#define DPP_XOR1   0xB1  // quad_perm(1,0,3,2)
#define DPP_XOR2   0x4E  // quad_perm(2,3,0,1)
#define DPP_RSHR4  0x114 // row_shr:4  (dst[s]=src[s-4] within 16-row, 0 for s<4)
#define DPP_ROR4   0x124
#define DPP_ROR8   0x128
#define DPP_BC15   0x142
#define DPP_BC31   0x143

constexpr float LOG2E = 1.4426950408889634f;
constexpr float LN2   = 0.6931471805599453f;

// R9: dual-role threads — 256 threads / 4 waves per block; each thread runs
// TWO independent instances (role A: state jA, role B: state jB = jA+64) of
// the verified R2/R8 per-thread code.  Why: R1/R2/R8 (three structurally
// different kernels) all hit ~760-800us -> fixed per-step cost = 8-wave
// barrier machinery + serial chain with no independent work to overlap
// (2 lockstep waves/SIMD, R3).  This halves waves per barrier (8->4) AND
// gives each wave two independent dependency chains (intra-wave ILP).
// U-broadcast ds_reads are shared by both roles (LDS read ops halve).
// All DPP lane patterns are wave-index-free -> reused verbatim per role.
// VGPR ~280 at 1 wave/SIMD (launch_bounds(256,1) -> 512-reg budget; the
// 64-VGPR clamp of R4-R6 was specific to 1024-thread workgroups).
// Math per role: G-factored raw ring, modulo-scheduled 8-step body with
// frame rotation (R8), tail-pipelined dur-sum, barrier at step bottom.
struct Role {
    f2    rp[16];    // raw ring (rotating frame)
    f2    eApk[16];  // eApk[cp*4+m] = (eA[8s+2m][j4+cp], eA[8s+2m+1][j4+cp])
    f2    eDp[32];   // pair table: eDp[w] = (eD[w], eD[(w+1)&31]) for (j, q)
    float eD0;       // exp(D[j][0])
    float pf[4];     // logB prefetch, distance 4
    float e_pi;
    float G;         // cumulative scale within current 8-step rebase window
    float dsP;       // raw duration-sum for the upcoming step (from prev tail)
};

struct Ctx {
    const float4* up0; const float4* up1;  // U reads: 2 x float4 at group s (shared)
    const float*  wmp;                     // renorm read: &wmaxf[cc]
    float* uawA0; float* uawA1;            // U writes, role A (chunk-0 lanes)
    float* uawB0; float* uawB1;            // U writes, role B
    float* wmwp;                           // wave-max write (lane 63)
    bool q0, l63, b0, b1;                  // chunk0, lane63, l&1, l&2
};

__device__ __forceinline__ float trans_reduce(float4 va, float4 vb,
                                              const f2* eApk, bool b0, bool b1)
{
    f2 a0, a1, a2, a3, u;
    u = (f2){va.x, va.y};
    a0 = u * eApk[0];  a1 = u * eApk[4];  a2 = u * eApk[8];  a3 = u * eApk[12];
    u = (f2){va.z, va.w};
    a0 = pkfma(u, eApk[1], a0); a1 = pkfma(u, eApk[5], a1);
    a2 = pkfma(u, eApk[9], a2); a3 = pkfma(u, eApk[13], a3);
    u = (f2){vb.x, vb.y};
    a0 = pkfma(u, eApk[2], a0); a1 = pkfma(u, eApk[6], a1);
    a2 = pkfma(u, eApk[10], a2); a3 = pkfma(u, eApk[14], a3);
    u = (f2){vb.z, vb.w};
    a0 = pkfma(u, eApk[3], a0); a1 = pkfma(u, eApk[7], a1);
    a2 = pkfma(u, eApk[11], a2); a3 = pkfma(u, eApk[15], a3);
    // quad butterfly transpose-reduce: lane ends with its OWN state (cc=l&3)
    float h0 = a0.x + a0.y, h1 = a1.x + a1.y, h2 = a2.x + a2.y, h3 = a3.x + a3.y;
    float s1 = b0 ? h0 : h1;
    float k1 = b0 ? h1 : h0;
    float m01 = k1 + dppf<DPP_XOR1>(s1);
    float s2 = b0 ? h2 : h3;
    float k2 = b0 ? h3 : h2;
    float m23 = k2 + dppf<DPP_XOR1>(s2);
    float s3 = b1 ? m01 : m23;
    float k3 = b1 ? m23 : m01;
    float tp = k3 + dppf<DPP_XOR2>(s3);    // quad-sum of h_{l&3}
    tp += dppf<DPP_ROR4>(tp);
    tp += dppf<DPP_ROR8>(tp);              // full Etrans[j]
    return tp;
}

template<int P>
__device__ __forceinline__ void tail_dur(Role& R)
{
    constexpr int rhoN = 30 - P;           // tail insert reg (P=7 -> 23 -> 31 on rotate)
    float rold;
    if constexpr (rhoN & 1) rold = R.rp[rhoN >> 1].y; else rold = R.rp[rhoN >> 1].x;
    float ins = dppzf<DPP_RSHR4>(rold);    // carry from chunk q-1; chunk0 lanes get 0
    if constexpr (rhoN & 1) R.rp[rhoN >> 1].y = ins;
    else                    R.rp[rhoN >> 1].x = ins;

    f2 q0a = {0.f, 0.f}, q1a = {0.f, 0.f}, q2a = {0.f, 0.f}, q3a = {0.f, 0.f};
#pragma unroll
    for (int m2 = 0; m2 < 16; m2 += 4) {
        q0a = pkfma(R.rp[m2],     R.eDp[(2 * m2 + P + 2) & 31], q0a);
        q1a = pkfma(R.rp[m2 + 1], R.eDp[(2 * m2 + P + 4) & 31], q1a);
        q2a = pkfma(R.rp[m2 + 2], R.eDp[(2 * m2 + P + 6) & 31], q2a);
        q3a = pkfma(R.rp[m2 + 3], R.eDp[(2 * m2 + P + 8) & 31], q3a);
    }
    f2 qs = (q0a + q1a) + (q2a + q3a);
    float ds = qs.x + qs.y;
    ds += dppf<DPP_ROR4>(ds);
    ds += dppf<DPP_ROR8>(ds);              // sum over the 4 lag-chunk lanes (fixed cc)
    R.dsP = ds;
}

__device__ __forceinline__ void rotate_ring(Role& R)
{
    // frame rotation: new[(i+4)&15] = old[i]  (shift ring by 8 slots)
    f2 t12 = R.rp[12], t13 = R.rp[13], t14 = R.rp[14], t15 = R.rp[15];
    R.rp[15] = R.rp[11]; R.rp[14] = R.rp[10];
    R.rp[13] = R.rp[9];  R.rp[12] = R.rp[8];
    R.rp[11] = R.rp[7];  R.rp[10] = R.rp[6];
    R.rp[9]  = R.rp[5];  R.rp[8]  = R.rp[4];
    R.rp[7]  = R.rp[3];  R.rp[6]  = R.rp[2];
    R.rp[5]  = R.rp[1];  R.rp[4]  = R.rp[0];
    R.rp[3] = t15; R.rp[2] = t14; R.rp[1] = t13; R.rp[0] = t12;
}

template<int P>
__device__ __forceinline__ void hsmm_step(Role& RA, Role& RB, const Ctx& c,
                                          const float*& pfp, float& C2, int tb8)
{
    constexpr int  rho = 31 - P;           // this step's fresh slot (frame reg)
    constexpr int  pb  = (P + 1) & 1;
    constexpr int  wb  = P & 1;
    const int t = tb8 + P;

    // ---- U loads: 2 x b128 (8 floats), shared by both roles ----
    const float4* up = pb ? c.up1 : c.up0;
    float4 va = up[0];
    float4 vb = up[1];

    // ---- logB: consume depth-4 prefetch, refill with imm-offset loads ----
    float xA = RA.pf[P & 3];               // logB[t][jA]
    float xB = RB.pf[P & 3];               // logB[t][jB]
    if (t + 4 < TT) {
        RA.pf[P & 3] = pfp[P * SS];
        RB.pf[P & 3] = pfp[P * SS + 64];
    }

    // ---- step multipliers and scale bookkeeping ----
    float gA = fexp2(xA * LOG2E);
    float gB = fexp2(xB * LOG2E);
    if constexpr (P == 7) {
        float mv = *c.wmp;                 // one of 4 wave maxes (written at P==6)
        mv = fmaxf(mv, dppf<DPP_XOR1>(mv));
        mv = fmaxf(mv, dppf<DPP_XOR2>(mv));// max over all 4 waves (quad-combined)
        C2 += flog2(mv);
        float rm = frcp(mv);
        gA *= rm; gB *= rm;
        pfp += 8 * SS;
    }
    float rGA = frcp(RA.G), rGB = frcp(RB.G);
    float GnA = RA.G * gA;  RA.G = GnA;
    float GnB = RB.G * gB;  RB.G = GnB;

    // ---- trans (two independent chains) ----
    float tpA = trans_reduce(va, vb, RA.eApk, c.b0, c.b1);
    float tpB = trans_reduce(va, vb, RB.eApk, c.b0, c.b1);
    if constexpr (P == 0) { if (tb8 == 0) { tpA = RA.e_pi; tpB = RB.e_pi; } }

    // ---- join: U = G*raw_dur(lags>=2) + fresh lag-1 term; patch fresh slots ----
    float UA = fmaf(tpA * gA, RA.eD0, RA.dsP * GnA);
    float UB = fmaf(tpB * gB, RB.eD0, RB.dsP * GnB);
    if (c.q0) {
        float frA = tpA * rGA;             // raw entry = entry[t]/G_{t-1}
        float frB = tpB * rGB;
        if constexpr (rho & 1) { RA.rp[rho >> 1].y = frA; RB.rp[rho >> 1].y = frB; }
        else                   { RA.rp[rho >> 1].x = frA; RB.rp[rho >> 1].x = frB; }
        *(wb ? c.uawA1 : c.uawA0) = UA;
        *(wb ? c.uawB1 : c.uawB0) = UB;
    }

    // ---- wave max only on pre-renorm steps ----
    if constexpr (P == 6) {
        float wm = fmaxf(UA, UB);
        wm = fmaxf(wm, dppf<DPP_XOR1>(wm));
        wm = fmaxf(wm, dppf<DPP_XOR2>(wm));
        wm = fmaxf(wm, dppf<DPP_BC15>(wm));
        wm = fmaxf(wm, dppf<DPP_BC31>(wm));// lane63 = max over wave's 32 states
        if (c.l63) *c.wmwp = wm;
    }

    // ---- rebase once per 8-step block (fp32 range control) ----
    if constexpr (P == 7) {
        f2 GGA = {GnA, GnA}, GGB = {GnB, GnB};
#pragma unroll
        for (int m2 = 0; m2 < 16; ++m2) {
            RA.rp[m2] = RA.rp[m2] * GGA;
            RB.rp[m2] = RB.rp[m2] * GGB;
        }
        RA.G = 1.f; RB.G = 1.f;
    }

    // ---- TAIL (pre-barrier, register-only): insert + raw dur-sum for t+1 ----
    tail_dur<P>(RA);
    tail_dur<P>(RB);

    asm volatile("s_waitcnt lgkmcnt(0)\n\ts_barrier" ::: "memory");
}

__launch_bounds__(256, 1)
__global__ void hsmm_fwd_kernel(const float* __restrict__ logB,
                                const float* __restrict__ pi,
                                const float* __restrict__ Ag,
                                const float* __restrict__ Dg,
                                float* __restrict__ out)
{
    const int b    = blockIdx.x;
    const int tid  = threadIdx.x;          // 0..255
    const int l    = tid & 63;
    const int wv   = tid >> 6;             // wave 0..3
    const int r    = (l >> 4);
    const int sIdx = l & 15;
    const int cc   = l & 3;
    const int q    = (l >> 2) & 3;
    const int j4A  = wv * 16 + r * 4;
    const int jA   = j4A + cc;             // role A state (0..63)
    const int jB   = jA + 64;              // role B state (64..127)

    // U groups: group s (U[8s..8s+8)) at float offset 12*s (2-way bank alias = free)
    __shared__ __align__(16) float ua[2][16 * 12];
    __shared__ __align__(16) float wmaxf[4];

    Role RA, RB;
#pragma unroll
    for (int cp = 0; cp < 4; ++cp)
#pragma unroll
        for (int m = 0; m < 4; ++m) {
            RA.eApk[cp * 4 + m].x = fexp2(Ag[(8 * sIdx + 2 * m)     * SS + j4A + cp] * LOG2E);
            RA.eApk[cp * 4 + m].y = fexp2(Ag[(8 * sIdx + 2 * m + 1) * SS + j4A + cp] * LOG2E);
            RB.eApk[cp * 4 + m].x = fexp2(Ag[(8 * sIdx + 2 * m)     * SS + j4A + 64 + cp] * LOG2E);
            RB.eApk[cp * 4 + m].y = fexp2(Ag[(8 * sIdx + 2 * m + 1) * SS + j4A + 64 + cp] * LOG2E);
        }
    {
        float eDA[32], eDB[32];
#pragma unroll
        for (int k = 0; k < 32; ++k) {
            eDA[k] = fexp2(Dg[jA * DMAXX + q * 32 + k] * LOG2E);
            eDB[k] = fexp2(Dg[jB * DMAXX + q * 32 + k] * LOG2E);
        }
#pragma unroll
        for (int wdx = 0; wdx < 32; ++wdx) {
            RA.eDp[wdx].x = eDA[wdx];
            RA.eDp[wdx].y = eDA[(wdx + 1) & 31];
            RB.eDp[wdx].x = eDB[wdx];
            RB.eDp[wdx].y = eDB[(wdx + 1) & 31];
        }
    }
#pragma unroll
    for (int k = 0; k < 16; ++k) { RA.rp[k] = (f2){0.f, 0.f}; RB.rp[k] = (f2){0.f, 0.f}; }
    RA.eD0  = fexp2(Dg[jA * DMAXX] * LOG2E);
    RB.eD0  = fexp2(Dg[jB * DMAXX] * LOG2E);
    RA.e_pi = fexp2(pi[jA] * LOG2E);
    RB.e_pi = fexp2(pi[jB] * LOG2E);
    RA.G = 1.f; RB.G = 1.f;
    RA.dsP = 0.f; RB.dsP = 0.f;
    float C2 = 0.f;

    const float* __restrict__ lb = logB + ((size_t)b * TT) * SS + jA;
#pragma unroll
    for (int k = 0; k < 4; ++k) {
        RA.pf[k] = lb[(size_t)k * SS];
        RB.pf[k] = lb[(size_t)k * SS + 64];
    }
    const float* pfp = lb + (size_t)4 * SS;

    Ctx c;
    c.up0   = (const float4*)&ua[0][sIdx * 12];
    c.up1   = (const float4*)&ua[1][sIdx * 12];
    c.wmp   = &wmaxf[cc];
    c.q0    = (q == 0);
    c.l63   = (l == 63);
    c.b0    = (l & 1);
    c.b1    = ((l & 2) != 0);
    c.uawA0 = &ua[0][(jA >> 3) * 12 + (jA & 7)];
    c.uawA1 = &ua[1][(jA >> 3) * 12 + (jA & 7)];
    c.uawB0 = &ua[0][(jB >> 3) * 12 + (jB & 7)];
    c.uawB1 = &ua[1][(jB >> 3) * 12 + (jB & 7)];
    c.wmwp  = &wmaxf[wv];

#pragma unroll 1
    for (int tb8 = 0; tb8 < TT; tb8 += 8) {
        hsmm_step<0>(RA, RB, c, pfp, C2, tb8);
        hsmm_step<1>(RA, RB, c, pfp, C2, tb8);
        hsmm_step<2>(RA, RB, c, pfp, C2, tb8);
        hsmm_step<3>(RA, RB, c, pfp, C2, tb8);
        hsmm_step<4>(RA, RB, c, pfp, C2, tb8);
        hsmm_step<5>(RA, RB, c, pfp, C2, tb8);
        hsmm_step<6>(RA, RB, c, pfp, C2, tb8);
        hsmm_step<7>(RA, RB, c, pfp, C2, tb8);
        rotate_ring(RA);
        rotate_ring(RB);
    }

    // epilogue: out[b] = (C2 + log2(sum_j U_{T-1}[j])) * ln2 ;  (T-1)&1 == 1
    if (tid == 0) {
        float s = 0.f;
        for (int i = 0; i < SS; ++i) s += ua[1][(i >> 3) * 12 + (i & 7)];
        out[b] = (C2 + flog2(s)) * LN2;
    }
}

extern "C" void kernel_launch(void* const* d_in, const int* in_sizes, int n_in,
                              void* d_out, int out_size, void* d_ws, size_t ws_size,
                              hipStream_t stream) {
    const float* logB = (const float*)d_in[0];   // (64, 2048, 128) f32
    const float* pi   = (const float*)d_in[1];   // (128,) f32
    const float* A    = (const float*)d_in[2];   // (128, 128) f32
    const float* D    = (const float*)d_in[3];   // (128, 128) f32
    float* out        = (float*)d_out;           // (64,) f32
    hipLaunchKernelGGL(hsmm_fwd_kernel, dim3(NBATCH), dim3(256), 0, stream,
                       logB, pi, A, D, out);
}

// Round 10
// 837.564 us; speedup vs baseline: 1.2304x; 1.2304x over previous
//
#include <hip/hip_runtime.h>

#define TT 2048
#define SS 128
#define DMAXX 128
#define NBATCH 64

typedef float f2 __attribute__((ext_vector_type(2)));

__device__ __forceinline__ float fexp2(float x){ return __builtin_amdgcn_exp2f(x); }
__device__ __forceinline__ float flog2(float x){ return __builtin_amdgcn_logf(x); }
__device__ __forceinline__ float frcp (float x){ return __builtin_amdgcn_rcpf(x); }
__device__ __forceinline__ f2 pkfma(f2 a, f2 b, f2 c){ return __builtin_elementwise_fma(a, b, c); }

template<int CTRL>
__device__ __forceinline__ float dppf(float x) {
    int i = __float_as_int(x);
    return __int_as_float(__builtin_amdgcn_update_dpp(i, i, CTRL, 0xF, 0xF, false));
}
template<int CTRL>
__device__ __forceinline__ float dppzf(float x) {   // bound_ctrl: OOB source lanes read 0
    int i = __float_as_int(x);
    return __int_as_float(__builtin_amdgcn_update_dpp(0, i, CTRL, 0xF, 0xF, true));
}
#define DPP_XOR1   0xB1  // quad_perm(1,0,3,2)
#define DPP_XOR2   0x4E  // quad_perm(2,3,0,1)
#define DPP_RSHR4  0x114 // row_shr:4  (dst[s]=src[s-4] within 16-row, 0 for s<4)
#define DPP_ROR4   0x124
#define DPP_ROR8   0x128
#define DPP_BC15   0x142
#define DPP_BC31   0x143

constexpr float LOG2E = 1.4426950408889634f;
constexpr float LN2   = 0.6931471805599453f;

// R10 = R8 (best, 758us) with the trans butterfly ELIMINATED (own-state eApk
// layout) + 16-step modulo body.  Rationale: R8 is ~76% active-SIMD VALU
// busy (19.1% device / 25% active CUs) -> issue-bound; only instruction
// reduction moves the wall.  R9 proved 2 waves/SIMD TLP must be preserved.
//
// Own-state trans: lane (r, sIdx), q = sIdx>>2, owns state j = 16w+4r+(sIdx&3)
// and accumulates ONLY j's partial over U[32q..32q+32) (eApk[k] =
// (eA[32q+2k][j], eA[32q+2k+1][j])).  Reduce = 3 f2 adds + 1 + ror4 + ror8
// (sums the 4 distance-4 lanes = over q) vs old 4 h-adds + 12-op butterfly.
// Reads: 8 x ds_read_b128 (16-lane broadcast groups, 2-way bank alias=free).
// tp's uniformity group (same r,cc) now equals dsP's -> join/insert/write
// logic identical to R8.  -12 VALU/step, +6 ds issue slots.
// 16-step body: rotation cost 2/step (~12KB body, inside R8-verified I$ range);
// rebase/renorm cadence stays 8 (P==7,15); pfp advances at P==7,15 so global
// offsets (P&7)*512B fit the 13-bit imm field.
// Math: G-factored raw ring, tail-pipelined dur-sum, barrier at step bottom.
struct State {
    f2    rp[16];    // raw ring (rotating frame, shift 16/block)
    f2    eApk[16];  // eApk[k] = (eA[32q+2k][j], eA[32q+2k+1][j])
    f2    eDp[32];   // pair table: eDp[w] = (eD[w], eD[(w+1)&31]) for (j, q)
    float eD0;       // exp(D[j][0])
    float pf[4];     // logB prefetch, distance 4
    const float* pfp;
    float C2;
    float e_pi;
    float G;         // cumulative scale within current 8-step rebase window
    float dsP;       // raw duration-sum for the upcoming step (from prev tail)
};

struct Ctx {
    const float4* up0; const float4* up1;  // U reads: base at group 4q (float4 idx 12q)
    const f2*     wmp;                     // renorm read pair
    float* uaw0; float* uaw1;              // U write (chunk-0 lanes)
    float* wmwp;                           // wave-max write (lane 63)
    bool q0, l63;
};

__device__ __forceinline__ float trans_reduce(const float4* up, const f2* eApk)
{
    float4 v0 = up[0], v1 = up[1], v2 = up[3], v3 = up[4],
           v4 = up[6], v5 = up[7], v6 = up[9], v7 = up[10];
    f2 a0, a1, a2, a3, u;
    u = (f2){v0.x, v0.y}; a0 = u * eApk[0];
    u = (f2){v0.z, v0.w}; a1 = u * eApk[1];
    u = (f2){v1.x, v1.y}; a2 = u * eApk[2];
    u = (f2){v1.z, v1.w}; a3 = u * eApk[3];
    u = (f2){v2.x, v2.y}; a0 = pkfma(u, eApk[4],  a0);
    u = (f2){v2.z, v2.w}; a1 = pkfma(u, eApk[5],  a1);
    u = (f2){v3.x, v3.y}; a2 = pkfma(u, eApk[6],  a2);
    u = (f2){v3.z, v3.w}; a3 = pkfma(u, eApk[7],  a3);
    u = (f2){v4.x, v4.y}; a0 = pkfma(u, eApk[8],  a0);
    u = (f2){v4.z, v4.w}; a1 = pkfma(u, eApk[9],  a1);
    u = (f2){v5.x, v5.y}; a2 = pkfma(u, eApk[10], a2);
    u = (f2){v5.z, v5.w}; a3 = pkfma(u, eApk[11], a3);
    u = (f2){v6.x, v6.y}; a0 = pkfma(u, eApk[12], a0);
    u = (f2){v6.z, v6.w}; a1 = pkfma(u, eApk[13], a1);
    u = (f2){v7.x, v7.y}; a2 = pkfma(u, eApk[14], a2);
    u = (f2){v7.z, v7.w}; a3 = pkfma(u, eApk[15], a3);
    f2 qs = (a0 + a1) + (a2 + a3);
    float tp = qs.x + qs.y;                // own-state partial over 32 U
    tp += dppf<DPP_ROR4>(tp);
    tp += dppf<DPP_ROR8>(tp);              // + the other 3 q-chunks -> full Etrans[j]
    return tp;
}

template<int P>
__device__ __forceinline__ void hsmm_step(State& st, const Ctx& c, int tb16)
{
    constexpr int  rho    = 31 - P;        // this step's fresh slot (frame reg)
    constexpr int  rhoN   = 30 - P;        // tail insert reg (P=15 -> 15 -> 31 on rotate)
    constexpr int  pb     = (P + 1) & 1;
    constexpr int  wb     = P & 1;
    constexpr bool DO_WM  = ((P & 7) == 6);
    constexpr bool DO_RN  = ((P & 7) == 7);
    const int t = tb16 + P;

    // ---- logB: consume depth-4 prefetch, refill with imm-offset load ----
    float xB = st.pf[P & 3];               // logB[t], loaded 4 steps ago
    if (t + 4 < TT) st.pf[P & 3] = st.pfp[(P & 7) * SS];
    if constexpr (DO_RN) st.pfp += 8 * SS;

    // ---- step multiplier g and scale bookkeeping ----
    float g = fexp2(xB * LOG2E);
    if constexpr (DO_RN) {
        f2 wv = *c.wmp;
        float m = fmaxf(wv.x, wv.y);
        m = fmaxf(m, dppf<DPP_XOR1>(m));
        m = fmaxf(m, dppf<DPP_XOR2>(m));   // max over all 8 waves (quad-combined)
        st.C2 += flog2(m);
        g *= frcp(m);
    }
    float rG = frcp(st.G);                 // 1/G_{t-1}
    float Gn = st.G * g;                   // G_t
    st.G = Gn;

    // ---- trans: own-state accumulate + ror4/ror8 over q-chunks ----
    float tp = trans_reduce(pb ? c.up1 : c.up0, st.eApk);
    if constexpr (P == 0) { if (tb16 == 0) tp = st.e_pi; }   // t==0: entry = pi

    // ---- join: U = G*raw_dur(lags>=2) + fresh lag-1 term; patch fresh slot ----
    float U = fmaf(tp * g, st.eD0, st.dsP * Gn);
    if (c.q0) {
        float fr = tp * rG;                // raw entry value = entry[t]/G_{t-1}
        if constexpr (rho & 1) st.rp[rho >> 1].y = fr;
        else                   st.rp[rho >> 1].x = fr;
        *(wb ? c.uaw1 : c.uaw0) = U;
    }

    // ---- wave max only on pre-renorm steps ----
    if constexpr (DO_WM) {
        float wm = U;
        wm = fmaxf(wm, dppf<DPP_XOR1>(wm));
        wm = fmaxf(wm, dppf<DPP_XOR2>(wm));
        wm = fmaxf(wm, dppf<DPP_BC15>(wm));
        wm = fmaxf(wm, dppf<DPP_BC31>(wm));
        if (c.l63) *c.wmwp = wm;
    }

    // ---- rebase every 8 steps (fp32 range control) ----
    if constexpr (DO_RN) {
        f2 GG = {Gn, Gn};
#pragma unroll
        for (int m2 = 0; m2 < 16; ++m2) st.rp[m2] = st.rp[m2] * GG;
        st.G = 1.f;
    }

    // ---- TAIL (pre-barrier, register-only): insert + raw dur-sum for step t+1 ----
    float rold;
    if constexpr (rhoN & 1) rold = st.rp[rhoN >> 1].y; else rold = st.rp[rhoN >> 1].x;
    float ins = dppzf<DPP_RSHR4>(rold);    // carry from chunk q-1; chunk0 lanes get 0
    if constexpr (rhoN & 1) st.rp[rhoN >> 1].y = ins;
    else                    st.rp[rhoN >> 1].x = ins;

    f2 q0a = {0.f, 0.f}, q1a = {0.f, 0.f}, q2a = {0.f, 0.f}, q3a = {0.f, 0.f};
#pragma unroll
    for (int m2 = 0; m2 < 16; m2 += 4) {
        q0a = pkfma(st.rp[m2],     st.eDp[(2 * m2 + P + 2) & 31], q0a);
        q1a = pkfma(st.rp[m2 + 1], st.eDp[(2 * m2 + P + 4) & 31], q1a);
        q2a = pkfma(st.rp[m2 + 2], st.eDp[(2 * m2 + P + 6) & 31], q2a);
        q3a = pkfma(st.rp[m2 + 3], st.eDp[(2 * m2 + P + 8) & 31], q3a);
    }
    f2 qs = (q0a + q1a) + (q2a + q3a);
    float ds = qs.x + qs.y;
    ds += dppf<DPP_ROR4>(ds);
    ds += dppf<DPP_ROR8>(ds);              // sum over the 4 lag-chunk lanes (fixed cc)
    st.dsP = ds;

    asm volatile("s_waitcnt lgkmcnt(0)\n\ts_barrier" ::: "memory");
}

__launch_bounds__(512, 2)
__global__ void hsmm_fwd_kernel(const float* __restrict__ logB,
                                const float* __restrict__ pi,
                                const float* __restrict__ A,
                                const float* __restrict__ D,
                                float* __restrict__ out)
{
    const int b    = blockIdx.x;
    const int tid  = threadIdx.x;
    const int l    = tid & 63;
    const int w    = tid >> 6;
    const int r    = (l >> 4);
    const int sIdx = l & 15;
    const int cc   = l & 3;
    const int q    = (l >> 2) & 3;         // == sIdx>>2: lag-chunk AND trans U-chunk
    const int j4   = w * 16 + r * 4;
    const int j    = j4 + cc;

    // U groups: group s (U[8s..8s+8)) at float offset 12*s (2-way bank alias = free)
    __shared__ __align__(16) float ua[2][16 * 12];
    __shared__ __align__(16) float wmaxf[8];

    State st;
#pragma unroll
    for (int k = 0; k < 16; ++k) {
        st.eApk[k].x = fexp2(A[(32 * q + 2 * k)     * SS + j] * LOG2E);
        st.eApk[k].y = fexp2(A[(32 * q + 2 * k + 1) * SS + j] * LOG2E);
    }
    {
        float eD[32];
#pragma unroll
        for (int k = 0; k < 32; ++k)
            eD[k] = fexp2(D[j * DMAXX + q * 32 + k] * LOG2E);
#pragma unroll
        for (int wdx = 0; wdx < 32; ++wdx) {
            st.eDp[wdx].x = eD[wdx];
            st.eDp[wdx].y = eD[(wdx + 1) & 31];
        }
    }
#pragma unroll
    for (int k = 0; k < 16; ++k) st.rp[k] = (f2){0.f, 0.f};
    st.eD0  = fexp2(D[j * DMAXX] * LOG2E);
    st.C2   = 0.f;
    st.e_pi = fexp2(pi[j] * LOG2E);
    st.G    = 1.f;
    st.dsP  = 0.f;

    const float* __restrict__ lb = logB + ((size_t)b * TT) * SS + j;
#pragma unroll
    for (int k = 0; k < 4; ++k) st.pf[k] = lb[(size_t)k * SS];
    st.pfp = lb + (size_t)4 * SS;

    Ctx c;
    c.up0  = (const float4*)&ua[0][48 * q];   // float4 index 12q = group 4q
    c.up1  = (const float4*)&ua[1][48 * q];
    c.wmp  = (const f2*)&wmaxf[2 * cc];
    c.q0   = (q == 0);
    c.l63  = (l == 63);
    c.uaw0 = &ua[0][(j >> 3) * 12 + (j & 7)];
    c.uaw1 = &ua[1][(j >> 3) * 12 + (j & 7)];
    c.wmwp = &wmaxf[w];

#pragma unroll 1
    for (int tb16 = 0; tb16 < TT; tb16 += 16) {
        hsmm_step< 0>(st, c, tb16); hsmm_step< 1>(st, c, tb16);
        hsmm_step< 2>(st, c, tb16); hsmm_step< 3>(st, c, tb16);
        hsmm_step< 4>(st, c, tb16); hsmm_step< 5>(st, c, tb16);
        hsmm_step< 6>(st, c, tb16); hsmm_step< 7>(st, c, tb16);
        hsmm_step< 8>(st, c, tb16); hsmm_step< 9>(st, c, tb16);
        hsmm_step<10>(st, c, tb16); hsmm_step<11>(st, c, tb16);
        hsmm_step<12>(st, c, tb16); hsmm_step<13>(st, c, tb16);
        hsmm_step<14>(st, c, tb16); hsmm_step<15>(st, c, tb16);
        // ---- frame rotation: new[(i+8)&15] = old[i]  (shift ring by 16 slots) ----
#pragma unroll
        for (int i = 0; i < 8; ++i) {
            f2 tmp = st.rp[i];
            st.rp[i] = st.rp[i + 8];
            st.rp[i + 8] = tmp;
        }
    }

    // epilogue: out[b] = (C2 + log2(sum_j U_{T-1}[j])) * ln2 ;  (T-1)&1 == 1
    if (tid == 0) {
        float s = 0.f;
        for (int i = 0; i < SS; ++i) s += ua[1][(i >> 3) * 12 + (i & 7)];
        out[b] = (st.C2 + flog2(s)) * LN2;
    }
}

extern "C" void kernel_launch(void* const* d_in, const int* in_sizes, int n_in,
                              void* d_out, int out_size, void* d_ws, size_t ws_size,
                              hipStream_t stream) {
    const float* logB = (const float*)d_in[0];   // (64, 2048, 128) f32
    const float* pi   = (const float*)d_in[1];   // (128,) f32
    const float* A    = (const float*)d_in[2];   // (128, 128) f32
    const float* D    = (const float*)d_in[3];   // (128, 128) f32
    float* out        = (float*)d_out;           // (64,) f32
    hipLaunchKernelGGL(hsmm_fwd_kernel, dim3(NBATCH), dim3(512), 0, stream,
                       logB, pi, A, D, out);
}

// Round 11
// 825.824 us; speedup vs baseline: 1.2479x; 1.0142x over previous
//
#include <hip/hip_runtime.h>

#define TT 2048
#define SS 128
#define DMAXX 128
#define NBATCH 64

typedef float f2 __attribute__((ext_vector_type(2)));

__device__ __forceinline__ float fexp2(float x){ return __builtin_amdgcn_exp2f(x); }
__device__ __forceinline__ float flog2(float x){ return __builtin_amdgcn_logf(x); }
__device__ __forceinline__ float frcp (float x){ return __builtin_amdgcn_rcpf(x); }
__device__ __forceinline__ f2 pkfma(f2 a, f2 b, f2 c){ return __builtin_elementwise_fma(a, b, c); }

template<int CTRL>
__device__ __forceinline__ float dppf(float x) {
    int i = __float_as_int(x);
    return __int_as_float(__builtin_amdgcn_update_dpp(i, i, CTRL, 0xF, 0xF, false));
}
template<int CTRL>
__device__ __forceinline__ float dppzf(float x) {   // bound_ctrl: OOB source lanes read 0
    int i = __float_as_int(x);
    return __int_as_float(__builtin_amdgcn_update_dpp(0, i, CTRL, 0xF, 0xF, true));
}
#define DPP_XOR1   0xB1  // quad_perm(1,0,3,2)
#define DPP_XOR2   0x4E  // quad_perm(2,3,0,1)
#define DPP_RSHR4  0x114 // row_shr:4  (dst[s]=src[s-4] within 16-row, 0 for s<4)
#define DPP_ROR4   0x124
#define DPP_ROR8   0x128
#define DPP_BC15   0x142
#define DPP_BC31   0x143

constexpr float LOG2E = 1.4426950408889634f;
constexpr float LN2   = 0.6931471805599453f;

// R11 = R8 verbatim (measured best, 758us).  Session ledger:
//   R10 post-mortem: -19% VALU issue -> wall +2% => latency-bound, not
//   issue-bound; R3: chain reordering null; R7: prefetch depth null;
//   R9: 1 wave/SIMD loses co-issue TLP (+28%); R4-R6: 1024-thread VGPR
//   clamp forces spill (and fewer-CU pairing is structurally zero-sum).
//   The per-step wall (~888cy) is the irreducible cross-wave exchange
//   chain {barrier, ds_read, fma tree, DPP reduce, join, ds_write, drain}
//   at 8-wave lockstep, 1 block/CU, 64/256 CUs active by problem shape.
// Structure: modulo-scheduled 8-step body (~6KB, I$-resident), frame-rotated
// raw ring (G-factored), tail-pipelined dur-sum, barrier at step bottom.
// Lane mapping: l=tid&63, w=tid>>6, r=l>>4, s=l&15, cc=l&3, q=(l>>2)&3.
// State j = 16w+4r+cc; lag-chunk q owns lags [32q+1..32q+32].
struct State {
    f2    rp[16];    // raw ring (rotating frame)
    f2    eApk[16];  // eApk[cp*4+m] = (eA[8s+2m][j4+cp], eA[8s+2m+1][j4+cp])
    f2    eDp[32];   // pair table: eDp[w] = (eD[w], eD[(w+1)&31]) for (j, q)
    float eD0;       // exp(D[j][0])
    float pf[4];     // logB prefetch, distance 4
    const float* pfp;  // = lb + (tb8+4)*SS at block start
    float C2;
    float e_pi;
    float G;         // cumulative scale within current 8-step rebase window
    float dsP;       // raw duration-sum for the upcoming step (from prev tail)
};

struct Ctx {
    const float4* up0; const float4* up1;  // U reads: 2 x float4 at group s
    const f2*     wmp;                     // renorm read pair
    float* uaw0; float* uaw1;              // U write (chunk-0 lanes)
    float* wmwp;                           // wave-max write (lane 63)
    bool q0, l63, b0, b1;                  // chunk0, lane63, l&1, l&2
};

template<int P>
__device__ __forceinline__ void hsmm_step(State& st, const Ctx& c, int tb8)
{
    constexpr int  rho    = 31 - P;        // this step's fresh slot (frame reg)
    constexpr int  rhoN   = 30 - P;        // tail insert reg (P=7 -> 23, moves to 31 on rotate)
    constexpr int  pb     = (P + 1) & 1;
    constexpr int  wb     = P & 1;
    constexpr bool DO_WM  = (P == 6);
    constexpr bool DO_RN  = (P == 7);
    constexpr bool REBASE = (P == 7);
    const int t = tb8 + P;

    // ---- U loads: 2 x b128 (8 floats), issued first ----
    const float4* up = pb ? c.up1 : c.up0;
    float4 va = up[0];
    float4 vb = up[1];

    // ---- logB: consume depth-4 prefetch, refill with imm-offset load ----
    float xB = st.pf[P & 3];               // logB[t], loaded 4 steps ago
    if (t + 4 < TT) st.pf[P & 3] = st.pfp[P * SS];
    if constexpr (P == 7) st.pfp += 8 * SS;

    // ---- step multiplier g and scale bookkeeping ----
    float g = fexp2(xB * LOG2E);
    if constexpr (DO_RN) {
        f2 wv = *c.wmp;
        float m = fmaxf(wv.x, wv.y);
        m = fmaxf(m, dppf<DPP_XOR1>(m));
        m = fmaxf(m, dppf<DPP_XOR2>(m));   // max over all 8 waves (quad-combined)
        st.C2 += flog2(m);
        g *= frcp(m);
    }
    float rG = frcp(st.G);                 // 1/G_{t-1}
    float Gn = st.G * g;                   // G_t
    st.G = Gn;

    // ---- trans partials: 4 states of this row x 8 U values (16 pkfma, depth 4) ----
    f2 a0, a1, a2, a3, u;
    u = (f2){va.x, va.y};
    a0 = u * st.eApk[0];  a1 = u * st.eApk[4];  a2 = u * st.eApk[8];  a3 = u * st.eApk[12];
    u = (f2){va.z, va.w};
    a0 = pkfma(u, st.eApk[1], a0); a1 = pkfma(u, st.eApk[5], a1);
    a2 = pkfma(u, st.eApk[9], a2); a3 = pkfma(u, st.eApk[13], a3);
    u = (f2){vb.x, vb.y};
    a0 = pkfma(u, st.eApk[2], a0); a1 = pkfma(u, st.eApk[6], a1);
    a2 = pkfma(u, st.eApk[10], a2); a3 = pkfma(u, st.eApk[14], a3);
    u = (f2){vb.z, vb.w};
    a0 = pkfma(u, st.eApk[3], a0); a1 = pkfma(u, st.eApk[7], a1);
    a2 = pkfma(u, st.eApk[11], a2); a3 = pkfma(u, st.eApk[15], a3);

    // ---- quad butterfly transpose-reduce: lane ends with its OWN state (cc=l&3) ----
    float h0 = a0.x + a0.y, h1 = a1.x + a1.y, h2 = a2.x + a2.y, h3 = a3.x + a3.y;
    float s1 = c.b0 ? h0 : h1;
    float k1 = c.b0 ? h1 : h0;
    float m01 = k1 + dppf<DPP_XOR1>(s1);
    float s2 = c.b0 ? h2 : h3;
    float k2 = c.b0 ? h3 : h2;
    float m23 = k2 + dppf<DPP_XOR1>(s2);
    float s3 = c.b1 ? m01 : m23;
    float k3 = c.b1 ? m23 : m01;
    float tp = k3 + dppf<DPP_XOR2>(s3);    // quad-sum of h_{l&3}
    tp += dppf<DPP_ROR4>(tp);
    tp += dppf<DPP_ROR8>(tp);              // full Etrans[j]
    if constexpr (P == 0) { if (tb8 == 0) tp = st.e_pi; }   // t==0: entry = pi

    // ---- join: U = G*raw_dur(lags>=2) + fresh lag-1 term; patch fresh slot ----
    float U = fmaf(tp * g, st.eD0, st.dsP * Gn);
    if (c.q0) {
        float fr = tp * rG;                // raw entry value = entry[t]/G_{t-1}
        if constexpr (rho & 1) st.rp[rho >> 1].y = fr;
        else                   st.rp[rho >> 1].x = fr;
        *(wb ? c.uaw1 : c.uaw0) = U;
    }

    // ---- wave max only on pre-renorm steps ----
    if constexpr (DO_WM) {
        float wm = U;
        wm = fmaxf(wm, dppf<DPP_XOR1>(wm));
        wm = fmaxf(wm, dppf<DPP_XOR2>(wm));
        wm = fmaxf(wm, dppf<DPP_BC15>(wm));
        wm = fmaxf(wm, dppf<DPP_BC31>(wm));
        if (c.l63) *c.wmwp = wm;
    }

    // ---- rebase once per 8-step block (fp32 range control) ----
    if constexpr (REBASE) {
        f2 GG = {Gn, Gn};
#pragma unroll
        for (int m2 = 0; m2 < 16; ++m2) st.rp[m2] = st.rp[m2] * GG;
        st.G = 1.f;
    }

    // ---- TAIL (pre-barrier, register-only): insert + raw dur-sum for step t+1 ----
    float rold;
    if constexpr (rhoN & 1) rold = st.rp[rhoN >> 1].y; else rold = st.rp[rhoN >> 1].x;
    float ins = dppzf<DPP_RSHR4>(rold);    // carry from chunk q-1; chunk0 lanes get 0
    if constexpr (rhoN & 1) st.rp[rhoN >> 1].y = ins;
    else                    st.rp[rhoN >> 1].x = ins;

    f2 q0a = {0.f, 0.f}, q1a = {0.f, 0.f}, q2a = {0.f, 0.f}, q3a = {0.f, 0.f};
#pragma unroll
    for (int m2 = 0; m2 < 16; m2 += 4) {
        q0a = pkfma(st.rp[m2],     st.eDp[(2 * m2 + P + 2) & 31], q0a);
        q1a = pkfma(st.rp[m2 + 1], st.eDp[(2 * m2 + P + 4) & 31], q1a);
        q2a = pkfma(st.rp[m2 + 2], st.eDp[(2 * m2 + P + 6) & 31], q2a);
        q3a = pkfma(st.rp[m2 + 3], st.eDp[(2 * m2 + P + 8) & 31], q3a);
    }
    f2 qs = (q0a + q1a) + (q2a + q3a);
    float ds = qs.x + qs.y;
    ds += dppf<DPP_ROR4>(ds);
    ds += dppf<DPP_ROR8>(ds);              // sum over the 4 lag-chunk lanes (fixed cc)
    st.dsP = ds;

    asm volatile("s_waitcnt lgkmcnt(0)\n\ts_barrier" ::: "memory");
}

__launch_bounds__(512, 2)
__global__ void hsmm_fwd_kernel(const float* __restrict__ logB,
                                const float* __restrict__ pi,
                                const float* __restrict__ A,
                                const float* __restrict__ D,
                                float* __restrict__ out)
{
    const int b    = blockIdx.x;
    const int tid  = threadIdx.x;
    const int l    = tid & 63;
    const int w    = tid >> 6;
    const int r    = (l >> 4);
    const int sIdx = l & 15;
    const int cc   = l & 3;
    const int q    = (l >> 2) & 3;
    const int j4   = w * 16 + r * 4;
    const int j    = j4 + cc;

    // U groups: group s (U[8s..8s+8)) at float offset 12*s (2-way bank alias = free)
    __shared__ __align__(16) float ua[2][16 * 12];
    __shared__ __align__(16) float wmaxf[8];

    State st;
#pragma unroll
    for (int cp = 0; cp < 4; ++cp)
#pragma unroll
        for (int m = 0; m < 4; ++m) {
            st.eApk[cp * 4 + m].x = fexp2(A[(8 * sIdx + 2 * m)     * SS + j4 + cp] * LOG2E);
            st.eApk[cp * 4 + m].y = fexp2(A[(8 * sIdx + 2 * m + 1) * SS + j4 + cp] * LOG2E);
        }
    {
        float eD[32];
#pragma unroll
        for (int k = 0; k < 32; ++k)
            eD[k] = fexp2(D[j * DMAXX + q * 32 + k] * LOG2E);
#pragma unroll
        for (int wdx = 0; wdx < 32; ++wdx) {
            st.eDp[wdx].x = eD[wdx];
            st.eDp[wdx].y = eD[(wdx + 1) & 31];
        }
    }
#pragma unroll
    for (int k = 0; k < 16; ++k) st.rp[k] = (f2){0.f, 0.f};
    st.eD0  = fexp2(D[j * DMAXX] * LOG2E);
    st.C2   = 0.f;
    st.e_pi = fexp2(pi[j] * LOG2E);
    st.G    = 1.f;
    st.dsP  = 0.f;

    const float* __restrict__ lb = logB + ((size_t)b * TT) * SS + j;
#pragma unroll
    for (int k = 0; k < 4; ++k) st.pf[k] = lb[(size_t)k * SS];
    st.pfp = lb + (size_t)4 * SS;

    Ctx c;
    c.up0  = (const float4*)&ua[0][sIdx * 12];
    c.up1  = (const float4*)&ua[1][sIdx * 12];
    c.wmp  = (const f2*)&wmaxf[2 * cc];
    c.q0   = (q == 0);
    c.l63  = (l == 63);
    c.b0   = (l & 1);
    c.b1   = ((l & 2) != 0);
    c.uaw0 = &ua[0][(j >> 3) * 12 + (j & 7)];
    c.uaw1 = &ua[1][(j >> 3) * 12 + (j & 7)];
    c.wmwp = &wmaxf[w];

#pragma unroll 1
    for (int tb8 = 0; tb8 < TT; tb8 += 8) {
        hsmm_step<0>(st, c, tb8); hsmm_step<1>(st, c, tb8);
        hsmm_step<2>(st, c, tb8); hsmm_step<3>(st, c, tb8);
        hsmm_step<4>(st, c, tb8); hsmm_step<5>(st, c, tb8);
        hsmm_step<6>(st, c, tb8); hsmm_step<7>(st, c, tb8);
        // ---- frame rotation: new[(i+4)&15] = old[i]  (shift ring by 8 slots) ----
        {
            f2 t12 = st.rp[12], t13 = st.rp[13], t14 = st.rp[14], t15 = st.rp[15];
            st.rp[15] = st.rp[11]; st.rp[14] = st.rp[10];
            st.rp[13] = st.rp[9];  st.rp[12] = st.rp[8];
            st.rp[11] = st.rp[7];  st.rp[10] = st.rp[6];
            st.rp[9]  = st.rp[5];  st.rp[8]  = st.rp[4];
            st.rp[7]  = st.rp[3];  st.rp[6]  = st.rp[2];
            st.rp[5]  = st.rp[1];  st.rp[4]  = st.rp[0];
            st.rp[3] = t15; st.rp[2] = t14; st.rp[1] = t13; st.rp[0] = t12;
        }
    }

    // epilogue: out[b] = (C2 + log2(sum_j U_{T-1}[j])) * ln2 ;  (T-1)&1 == 1
    if (tid == 0) {
        float s = 0.f;
        for (int i = 0; i < SS; ++i) s += ua[1][(i >> 3) * 12 + (i & 7)];
        out[b] = (st.C2 + flog2(s)) * LN2;
    }
}

extern "C" void kernel_launch(void* const* d_in, const int* in_sizes, int n_in,
                              void* d_out, int out_size, void* d_ws, size_t ws_size,
                              hipStream_t stream) {
    const float* logB = (const float*)d_in[0];   // (64, 2048, 128) f32
    const float* pi   = (const float*)d_in[1];   // (128,) f32
    const float* A    = (const float*)d_in[2];   // (128, 128) f32
    const float* D    = (const float*)d_in[3];   // (128, 128) f32
    float* out        = (float*)d_out;           // (64,) f32
    hipLaunchKernelGGL(hsmm_fwd_kernel, dim3(NBATCH), dim3(512), 0, stream,
                       logB, pi, A, D, out);
}